// Round 11
// baseline (317.616 us; speedup 1.0000x reference)
//
#include <hip/hip_runtime.h>
#include <hip/hip_bf16.h>
#include <math.h>

#define BD 2
#define HD 16
#define NSEQ 8192
#define DDIM 64
#define NPROJ 7
#define KBLK 256
#define NSAMP 256
#define NBH (BD*HD)           // 32
#define NB (NSEQ/KBLK)        // 32

typedef short bf16x8 __attribute__((ext_vector_type(8)));
typedef short bf16x4 __attribute__((ext_vector_type(4)));
typedef float f32x4 __attribute__((ext_vector_type(4)));

// pack two f32 -> u32 of 2 bf16 (RTNE via v_cvt_pk_bf16_f32)
__device__ __forceinline__ unsigned int pk2bf(float a, float b) {
    union { __hip_bfloat162 h; unsigned int u; } t;
    t.h = __float22bfloat162_rn(make_float2(a, b));
    return t.u;
}

// async global->LDS touch (16B). Used ONLY as an L2 prefetch: dest is a
// scrap LDS buffer, data never read. Zero VGPR cost; drained by barrier.
__device__ __forceinline__ void gload16(const void* gsrc, void* lds) {
    __builtin_amdgcn_global_load_lds(
        (const __attribute__((address_space(1))) unsigned int*)gsrc,
        (__attribute__((address_space(3))) unsigned int*)lds, 16, 0, 0);
}

// ---------------------------------------------------------------------------
// Kernel A (fused prelude): q-hash + k-dots + k-norm + per-bh max-norm.
// Dot/norm accumulation kept IDENTICAL across rounds (hash sign bits are
// exact-match-critical).
// ---------------------------------------------------------------------------
__global__ __launch_bounds__(256) void prelude_kernel(const float* __restrict__ q,
                                                      const float* __restrict__ k,
                                                      const float* __restrict__ pd,
                                                      float* __restrict__ kdots,
                                                      unsigned int* __restrict__ kmax_bits,
                                                      unsigned char* __restrict__ qh) {
    __shared__ float pds[(DDIM+1)*NPROJ];
    __shared__ float red[256];
    const int tid = threadIdx.x;
    for (int i = tid; i < (DDIM+1)*NPROJ; i += 256) pds[i] = pd[i];
    __syncthreads();

    const int lin = blockIdx.x * 256 + tid;
    const int bh = lin >> 13;

    float acc[NPROJ];
    float4 xv[16];

    {
        const float4* xp = (const float4*)(q + (size_t)lin * DDIM);
        #pragma unroll
        for (int j = 0; j < 16; ++j) xv[j] = xp[j];
        #pragma unroll
        for (int r = 0; r < NPROJ; ++r) acc[r] = 0.f;
        #pragma unroll
        for (int j = 0; j < 16; ++j) {
            float xs[4] = {xv[j].x, xv[j].y, xv[j].z, xv[j].w};
            #pragma unroll
            for (int c = 0; c < 4; ++c) {
                const int d = j*4 + c;
                #pragma unroll
                for (int r = 0; r < NPROJ; ++r) acc[r] += xs[c] * pds[d*NPROJ + r];
            }
        }
        int bin = 0;
        #pragma unroll
        for (int r = 0; r < NPROJ; ++r) bin |= (acc[r] > 0.f) << r;
        qh[lin] = (unsigned char)(bin ^ (bin >> 1));
    }

    float nr;
    {
        const float4* xp = (const float4*)(k + (size_t)lin * DDIM);
        #pragma unroll
        for (int j = 0; j < 16; ++j) xv[j] = xp[j];
        #pragma unroll
        for (int r = 0; r < NPROJ; ++r) acc[r] = 0.f;
        #pragma unroll
        for (int j = 0; j < 16; ++j) {
            float xs[4] = {xv[j].x, xv[j].y, xv[j].z, xv[j].w};
            #pragma unroll
            for (int c = 0; c < 4; ++c) {
                const int d = j*4 + c;
                #pragma unroll
                for (int r = 0; r < NPROJ; ++r) acc[r] += xs[c] * pds[d*NPROJ + r];
            }
        }
        float ss = 0.f;
        #pragma unroll
        for (int j = 0; j < 16; ++j) {
            float4 t = xv[j];
            ss += t.x*t.x + t.y*t.y + t.z*t.z + t.w*t.w;
        }
        nr = sqrtf(ss);
        float4* kd = (float4*)(kdots + (size_t)lin * 8);
        kd[0] = make_float4(acc[0], acc[1], acc[2], acc[3]);
        kd[1] = make_float4(acc[4], acc[5], acc[6], nr);
    }

    red[tid] = nr;
    __syncthreads();
    for (int s = 128; s > 0; s >>= 1) {
        if (tid < s) red[tid] = fmaxf(red[tid], red[tid+s]);
        __syncthreads();
    }
    if (tid == 0) atomicMax(&kmax_bits[bh], __float_as_uint(red[0]));
}

// ---------------------------------------------------------------------------
// Kernel B: k-hash from stored dots + kmax
// ---------------------------------------------------------------------------
__global__ __launch_bounds__(256) void khash_kernel(const float* __restrict__ pd,
                                                    const float* __restrict__ kdots,
                                                    const unsigned int* __restrict__ kmax_bits,
                                                    unsigned char* __restrict__ kh) {
    const int lin = blockIdx.x * 256 + threadIdx.x;
    const int bh = lin >> 13;
    const float4* kd = (const float4*)(kdots + (size_t)lin * 8);
    float4 d0 = kd[0], d1 = kd[1];
    float acc[NPROJ] = {d0.x, d0.y, d0.z, d0.w, d1.x, d1.y, d1.z};
    const float kn = d1.w;
    const float km = __uint_as_float(kmax_bits[bh]);
    const float ex = sqrtf(fmaxf(km*km - kn*kn, 0.f));
    int bin = 0;
    #pragma unroll
    for (int r = 0; r < NPROJ; ++r) {
        acc[r] += ex * pd[DDIM*NPROJ + r];
        bin |= (acc[r] > 0.f) << r;
    }
    kh[lin] = (unsigned char)(bin ^ (bin >> 1));
}

// ---------------------------------------------------------------------------
// Kernel C: parallel stable counting sort (128 buckets), 256 segs x 32 elems.
// ---------------------------------------------------------------------------
__global__ __launch_bounds__(256) void sort_kernel(const unsigned char* __restrict__ qhash,
                                                   const unsigned char* __restrict__ khash,
                                                   int* __restrict__ qidx,
                                                   int* __restrict__ kidx) {
    __shared__ unsigned char hsh[NSEQ];
    __shared__ unsigned short cnt[128][264];
    __shared__ int base[128];
    __shared__ int wtot[2];
    const int bh = blockIdx.x, tid = threadIdx.x;
    const unsigned char* hash = blockIdx.y ? khash : qhash;
    int* idx = blockIdx.y ? kidx : qidx;

    {
        const uint4* src = (const uint4*)(hash + (size_t)bh * NSEQ);
        uint4* hdst = (uint4*)hsh;
        hdst[tid] = src[tid];
        hdst[tid + 256] = src[tid + 256];
        unsigned int* cz = (unsigned int*)&cnt[0][0];
        for (int i = tid; i < 128*264/2; i += 256) cz[i] = 0;
    }
    __syncthreads();
    {
        const unsigned char* s = hsh + tid*32;
        for (int i = 0; i < 32; ++i) cnt[s[i]][tid]++;
    }
    __syncthreads();

    int sc = 0, vv = 0;
    if (tid < 128) {
        unsigned run = 0;
        uint4* rp = (uint4*)cnt[tid];
        for (int wd = 0; wd < 32; ++wd) {
            uint4 x = rp[wd];
            unsigned v0 = x.x & 0xffffu, v1 = x.x >> 16;
            unsigned v2 = x.y & 0xffffu, v3 = x.y >> 16;
            unsigned v4 = x.z & 0xffffu, v5 = x.z >> 16;
            unsigned v6 = x.w & 0xffffu, v7 = x.w >> 16;
            unsigned p0 = run, p1 = p0+v0, p2 = p1+v1, p3 = p2+v2,
                     p4 = p3+v3, p5 = p4+v4, p6 = p5+v5, p7 = p6+v6;
            run = p7 + v7;
            x.x = p0 | (p1<<16); x.y = p2 | (p3<<16);
            x.z = p4 | (p5<<16); x.w = p6 | (p7<<16);
            rp[wd] = x;
        }
        vv = (int)run;
        sc = vv;
        #pragma unroll
        for (int d = 1; d < 64; d <<= 1) {
            int t = __shfl_up(sc, d, 64);
            if ((tid & 63) >= d) sc += t;
        }
        if ((tid & 63) == 63) wtot[tid >> 6] = sc;
    }
    __syncthreads();
    if (tid < 128) base[tid] = (sc - vv) + (tid >= 64 ? wtot[0] : 0);
    __syncthreads();
    {
        int* dst = idx + (size_t)bh * NSEQ;
        const unsigned char* s = hsh + tid*32;
        for (int i = 0; i < 32; ++i) {
            int h = s[i];
            int c = cnt[h][tid];
            cnt[h][tid] = (unsigned short)(c + 1);
            dst[base[h] + c] = tid*32 + i;
        }
    }
}

#define VSWZ(d) ((((d) >> 1) & 7) << 4)

// ---------------------------------------------------------------------------
// Kernel C2 (respack): residual chunk LDS byte-images (unchanged expressions
// -> images byte-identical to in-kernel staging).
// ---------------------------------------------------------------------------
__global__ __launch_bounds__(256) void respack_kernel(const float* __restrict__ k,
                                                      const float* __restrict__ v,
                                                      const int* __restrict__ samp,
                                                      const int* __restrict__ kidx,
                                                      char* __restrict__ kres,
                                                      char* __restrict__ vres) {
    __shared__ int rows[64];
    const int bh = blockIdx.x, ch = blockIdx.y, tid = threadIdx.x;
    if (tid < 64) rows[tid] = kidx[bh*NSEQ + samp[bh*NSAMP + ch*64 + tid]];
    __syncthreads();
    const size_t basef = (size_t)bh * NSEQ * DDIM;
    char* kimg = kres + (size_t)(bh*4 + ch) * 8192;
    char* vimg = vres + (size_t)(bh*4 + ch) * 8192;

    {
        const int kk = tid & 63, dc = tid >> 6;
        const float* kr = k + basef + (size_t)rows[kk]*DDIM + dc*16;
        float4 f0 = ((const float4*)kr)[0], f1 = ((const float4*)kr)[1];
        float4 f2 = ((const float4*)kr)[2], f3 = ((const float4*)kr)[3];
        union { bf16x8 v8; unsigned int u[4]; } h0, h1;
        h0.u[0] = pk2bf(f0.x,f0.y); h0.u[1] = pk2bf(f0.z,f0.w);
        h0.u[2] = pk2bf(f1.x,f1.y); h0.u[3] = pk2bf(f1.z,f1.w);
        h1.u[0] = pk2bf(f2.x,f2.y); h1.u[1] = pk2bf(f2.z,f2.w);
        h1.u[2] = pk2bf(f3.x,f3.y); h1.u[3] = pk2bf(f3.z,f3.w);
        const int rb = kk*128 + dc*32, sw = (kk & 7) << 4;
        *(bf16x8*)(kimg + ((rb) ^ sw)) = h0.v8;
        *(bf16x8*)(kimg + ((rb + 16) ^ sw)) = h1.v8;
    }
    {
        const int vg = tid & 15, kq = tid >> 4;
        const int r0 = rows[kq*4 + 0], r1 = rows[kq*4 + 1];
        const int r2 = rows[kq*4 + 2], r3 = rows[kq*4 + 3];
        float4 x0 = *(const float4*)(v + basef + (size_t)r0*DDIM + vg*4);
        float4 x1 = *(const float4*)(v + basef + (size_t)r1*DDIM + vg*4);
        float4 x2 = *(const float4*)(v + basef + (size_t)r2*DDIM + vg*4);
        float4 x3 = *(const float4*)(v + basef + (size_t)r3*DDIM + vg*4);
        const float c0[4] = {x0.x, x0.y, x0.z, x0.w};
        const float c1[4] = {x1.x, x1.y, x1.z, x1.w};
        const float c2[4] = {x2.x, x2.y, x2.z, x2.w};
        const float c3[4] = {x3.x, x3.y, x3.z, x3.w};
        #pragma unroll
        for (int j = 0; j < 4; ++j) {
            const int d = vg*4 + j;
            unsigned h01 = pk2bf(c0[j], c1[j]);
            unsigned h23 = pk2bf(c2[j], c3[j]);
            *(uint2*)(vimg + ((d*128 + kq*8) ^ VSWZ(d))) = make_uint2(h01, h23);
        }
    }
}

// ---------------------------------------------------------------------------
// Kernel D: MFMA fused attention (round-8 compute core), CHUNK=128 staging
// (2 sub-chunks per barrier pair: halve barriers, double gather MLP) +
// zero-VGPR L2 prefetch of the next stage via dummy global_load_lds.
//   QK^T 16x16x32 (Q hi/lo); its C layout (q=lane&15, key=(lane>>4)*4+reg)
//   IS the B-operand layout of 16x16x16bf16_1k => PV from registers.
// ---------------------------------------------------------------------------

#define LN32 3.46573590279972f

template<int PHASE>   // 0 = block-diagonal, 1 = residual
__device__ __forceinline__ void compute_chunk(
    int ch, int lane,
    const bf16x8 (&qhf)[4][2], const bf16x8 (&qlf)[4][2],
    f32x4 (&O)[4][4], float (&lacc)[4],
    const float* maskF, const char* KhL, const char* VthL) {

    const int lr4 = lane >> 4;
    const int lc  = lane & 15;

    #pragma unroll
    for (int mt = 0; mt < 4; ++mt) {
        const int key = mt*16 + lc;
        const int ksw = (key & 7) << 4;
        bf16x8 ka0 = *(const bf16x8*)(KhL + ((key*128 +  0 + lr4*16) ^ ksw));
        bf16x8 ka1 = *(const bf16x8*)(KhL + ((key*128 + 64 + lr4*16) ^ ksw));
        float4 mk;
        if (PHASE) mk = *(const float4*)(maskF + ch*64 + mt*16 + lr4*4);

        bf16x4 pb[4];
        #pragma unroll
        for (int qt = 0; qt < 4; ++qt) {
            f32x4 c = {0.f, 0.f, 0.f, 0.f};
            c = __builtin_amdgcn_mfma_f32_16x16x32_bf16(ka0, qhf[qt][0], c, 0, 0, 0);
            c = __builtin_amdgcn_mfma_f32_16x16x32_bf16(ka0, qlf[qt][0], c, 0, 0, 0);
            c = __builtin_amdgcn_mfma_f32_16x16x32_bf16(ka1, qhf[qt][1], c, 0, 0, 0);
            c = __builtin_amdgcn_mfma_f32_16x16x32_bf16(ka1, qlf[qt][1], c, 0, 0, 0);
            float e0, e1, e2, e3;
            if (PHASE) {
                e0 = __expf(c[0] + LN32) * mk.x;
                e1 = __expf(c[1] + LN32) * mk.y;
                e2 = __expf(c[2] + LN32) * mk.z;
                e3 = __expf(c[3] + LN32) * mk.w;
            } else {
                e0 = __expf(c[0]); e1 = __expf(c[1]);
                e2 = __expf(c[2]); e3 = __expf(c[3]);
            }
            lacc[qt] += (e0+e1) + (e2+e3);
            union { bf16x4 v4; unsigned int u[2]; } pw;
            pw.u[0] = pk2bf(e0, e1);
            pw.u[1] = pk2bf(e2, e3);
            pb[qt] = pw.v4;
        }

        __builtin_amdgcn_s_setprio(1);
        #pragma unroll
        for (int dt = 0; dt < 4; ++dt) {
            const int d = dt*16 + lc;
            bf16x4 va = *(const bf16x4*)(VthL + ((d*128 + mt*32 + lr4*8) ^ VSWZ(d)));
            #pragma unroll
            for (int qt = 0; qt < 4; ++qt)
                O[qt][dt] = __builtin_amdgcn_mfma_f32_16x16x16bf16_1k(va, pb[qt], O[qt][dt], 0, 0, 0);
        }
        __builtin_amdgcn_s_setprio(0);
    }
}

__global__ __launch_bounds__(256, 2) void attn_kernel(const float* __restrict__ q,
                                                      const float* __restrict__ k,
                                                      const float* __restrict__ v,
                                                      const int* __restrict__ samp,
                                                      const int* __restrict__ qidx,
                                                      const int* __restrict__ kidx,
                                                      const char* __restrict__ kres,
                                                      const char* __restrict__ vres,
                                                      float* __restrict__ out) {
    __shared__ __align__(16) char KB[2][8192];
    __shared__ __align__(16) char VB[2][8192];
    __shared__ int qidxL[256];
    __shared__ int kidxL[256];
    __shared__ __align__(16) float maskF[256];
    __shared__ __align__(16) char PFD[1024];   // prefetch scrap (never read)

    const int g = blockIdx.x, bh = blockIdx.y;
    const int tid = threadIdx.x;
    const int lane = tid & 63, w = tid >> 6;
    const int lr4 = lane >> 4, lc = lane & 15;
    const size_t basef = (size_t)bh * NSEQ * DDIM;

    qidxL[tid] = qidx[bh*NSEQ + g*KBLK + tid];
    kidxL[tid] = kidx[bh*NSEQ + g*KBLK + tid];
    {
        int sp = samp[bh*NSAMP + tid];
        maskF[tid] = ((sp >> 8) == g) ? 0.f : 1.f;
    }
    __syncthreads();

    // Q fragments (hi/lo), pre-scaled by 0.125 (exact)
    bf16x8 qhf[4][2], qlf[4][2];
    #pragma unroll
    for (int qt = 0; qt < 4; ++qt) {
        const int qrow = qidxL[w*64 + qt*16 + lc];
        const float* qp = q + basef + (size_t)qrow*DDIM;
        #pragma unroll
        for (int ks = 0; ks < 2; ++ks) {
            const float* p = qp + ks*32 + lr4*8;
            float4 a = *(const float4*)p;
            float4 b = *(const float4*)(p + 4);
            float xs[8] = {a.x,a.y,a.z,a.w,b.x,b.y,b.z,b.w};
            union { bf16x8 v8; unsigned int u[4]; } hv, lv;
            #pragma unroll
            for (int j = 0; j < 4; ++j) {
                float s0 = xs[2*j]   * 0.125f;
                float s1 = xs[2*j+1] * 0.125f;
                unsigned hp = pk2bf(s0, s1);
                hv.u[j] = hp;
                float l0 = s0 - __uint_as_float(hp << 16);
                float l1 = s1 - __uint_as_float(hp & 0xffff0000u);
                lv.u[j] = pk2bf(l0, l1);
            }
            qhf[qt][ks] = hv.v8; qlf[qt][ks] = lv.v8;
        }
    }

    f32x4 O[4][4];
    #pragma unroll
    for (int a = 0; a < 4; ++a)
        #pragma unroll
        for (int b = 0; b < 4; ++b) O[a][b] = (f32x4){0.f,0.f,0.f,0.f};
    float lacc[4] = {0,0,0,0};

    // CHUNK=128 staging maps (image bytes identical to round-8 layout)
    const int kk2 = tid & 127, cck = kk2 >> 6, kkr = kk2 & 63, dc2 = tid >> 7;
    const int vg = tid & 15, m2 = tid >> 4;         // m2 in [0,16)
    const int ccv = m2 >> 3, kqb = (m2 & 7) * 2;

    // ==== PHASE 0: block-diagonal, 2 stages x 128 keys ====
    for (int st = 0; st < 2; ++st) {
        __syncthreads();
        // ---- K stage: thread -> 32 dims of one of 128 keys ----
        {
            const int row = kidxL[st*128 + kk2];
            const float* kr = k + basef + (size_t)row*DDIM + dc2*32;
            float4 f[8];
            #pragma unroll
            for (int i = 0; i < 8; ++i) f[i] = ((const float4*)kr)[i];
            const int sw2 = (kkr & 7) << 4;
            #pragma unroll
            for (int gi = 0; gi < 4; ++gi) {
                union { bf16x8 v8; unsigned int u[4]; } h;
                h.u[0] = pk2bf(f[2*gi].x,   f[2*gi].y);
                h.u[1] = pk2bf(f[2*gi].z,   f[2*gi].w);
                h.u[2] = pk2bf(f[2*gi+1].x, f[2*gi+1].y);
                h.u[3] = pk2bf(f[2*gi+1].z, f[2*gi+1].w);
                *(bf16x8*)(KB[cck] + ((kkr*128 + dc2*64 + gi*16) ^ sw2)) = h.v8;
            }
        }
        // ---- V stage: thread -> 4 dims x 8 rows (register transpose) ----
        {
            float4 x[8];
            #pragma unroll
            for (int i = 0; i < 8; ++i) {
                const int r = kidxL[st*128 + m2*8 + i];
                x[i] = *(const float4*)(v + basef + (size_t)r*DDIM + vg*4);
            }
            #pragma unroll
            for (int kqq = 0; kqq < 2; ++kqq) {
                const float c0[4] = {x[kqq*4+0].x, x[kqq*4+0].y, x[kqq*4+0].z, x[kqq*4+0].w};
                const float c1[4] = {x[kqq*4+1].x, x[kqq*4+1].y, x[kqq*4+1].z, x[kqq*4+1].w};
                const float c2[4] = {x[kqq*4+2].x, x[kqq*4+2].y, x[kqq*4+2].z, x[kqq*4+2].w};
                const float c3[4] = {x[kqq*4+3].x, x[kqq*4+3].y, x[kqq*4+3].z, x[kqq*4+3].w};
                #pragma unroll
                for (int j = 0; j < 4; ++j) {
                    const int d = vg*4 + j;
                    unsigned h01 = pk2bf(c0[j], c1[j]);
                    unsigned h23 = pk2bf(c2[j], c3[j]);
                    *(uint2*)(VB[ccv] + ((d*128 + (kqb + kqq)*8) ^ VSWZ(d))) = make_uint2(h01, h23);
                }
            }
        }
        __syncthreads();

        // ---- L2 prefetch of next stage (scrap LDS dest, zero VGPR) ----
        if (st == 0) {
            const int prow = kidxL[128 + (tid & 127)];
            const char* kb = (const char*)(k + basef) + (size_t)prow*256 + (tid >> 7)*128;
            const char* vb = (const char*)(v + basef) + (size_t)prow*256 + (tid >> 7)*128;
            gload16(kb, PFD);
            gload16(vb, PFD);
        } else {
            gload16(kres + (size_t)bh*32768 + tid*128, PFD);
            gload16(vres + (size_t)bh*32768 + tid*128, PFD);
        }

        compute_chunk<0>(st*2 + 0, lane, qhf, qlf, O, lacc, maskF, KB[0], VB[0]);
        compute_chunk<0>(st*2 + 1, lane, qhf, qlf, O, lacc, maskF, KB[1], VB[1]);
    }

    // ==== PHASE 1: residual (prepacked image copy), 2 stages x 2 images ====
    for (int st = 0; st < 2; ++st) {
        __syncthreads();
        #pragma unroll
        for (int cc = 0; cc < 2; ++cc) {
            const char* ksrc = kres + (size_t)(bh*4 + st*2 + cc) * 8192 + tid*32;
            const char* vsrc = vres + (size_t)(bh*4 + st*2 + cc) * 8192 + tid*32;
            float4 a0 = ((const float4*)ksrc)[0];
            float4 a1 = ((const float4*)ksrc)[1];
            float4 b0 = ((const float4*)vsrc)[0];
            float4 b1 = ((const float4*)vsrc)[1];
            *(float4*)(KB[cc] + tid*32)      = a0;
            *(float4*)(KB[cc] + tid*32 + 16) = a1;
            *(float4*)(VB[cc] + tid*32)      = b0;
            *(float4*)(VB[cc] + tid*32 + 16) = b1;
        }
        __syncthreads();
        compute_chunk<1>(st*2 + 0, lane, qhf, qlf, O, lacc, maskF, KB[0], VB[0]);
        compute_chunk<1>(st*2 + 1, lane, qhf, qlf, O, lacc, maskF, KB[1], VB[1]);
    }

    // ---- epilogue: O^T layout => q = lane&15 (matches lacc), d contiguous ----
    #pragma unroll
    for (int qt = 0; qt < 4; ++qt) {
        lacc[qt] += __shfl_xor(lacc[qt], 16, 64);
        lacc[qt] += __shfl_xor(lacc[qt], 32, 64);
        lacc[qt] = 1.f / lacc[qt];
    }
    float* ob = out + basef;
    #pragma unroll
    for (int qt = 0; qt < 4; ++qt) {
        const int orow = qidxL[w*64 + qt*16 + lc];
        const float f = lacc[qt];
        float* p = ob + (size_t)orow*DDIM + lr4*4;
        #pragma unroll
        for (int dt = 0; dt < 4; ++dt) {
            float4 st4 = make_float4(O[qt][dt][0]*f, O[qt][dt][1]*f,
                                     O[qt][dt][2]*f, O[qt][dt][3]*f);
            *(float4*)(p + dt*16) = st4;
        }
    }
}

// ---------------------------------------------------------------------------
extern "C" void kernel_launch(void* const* d_in, const int* in_sizes, int n_in,
                              void* d_out, int out_size, void* d_ws, size_t ws_size,
                              hipStream_t stream) {
    const float* q    = (const float*)d_in[0];
    const float* k    = (const float*)d_in[1];
    const float* v    = (const float*)d_in[2];
    const float* pd   = (const float*)d_in[3];
    const int*   samp = (const int*)d_in[4];
    float* out = (float*)d_out;

    char* ws = (char*)d_ws;
    // kdots occupies [0, 8 MB) and is dead after khash; qidx/kidx/kres/vres
    // overlay that region afterwards.
    float*         kdots = (float*)(ws + 0);
    int*           qidx  = (int*)(ws + 0);
    int*           kidx  = (int*)(ws + 1048576);
    char*          kres  = ws + 2097152;
    char*          vres  = ws + 3145728;
    unsigned char* qh    = (unsigned char*)(ws + 8388608);
    unsigned char* kh    = (unsigned char*)(ws + 8650752);
    unsigned int*  kmaxb = (unsigned int*)(ws + 8912896);

    hipMemsetAsync(kmaxb, 0, NBH*sizeof(unsigned int), stream);
    hipLaunchKernelGGL(prelude_kernel, dim3(NBH*NSEQ/256), dim3(256), 0, stream,
                       q, k, pd, kdots, kmaxb, qh);
    hipLaunchKernelGGL(khash_kernel, dim3(NBH*NSEQ/256), dim3(256), 0, stream,
                       pd, kdots, kmaxb, kh);
    hipLaunchKernelGGL(sort_kernel, dim3(NBH, 2), dim3(256), 0, stream, qh, kh, qidx, kidx);
    hipLaunchKernelGGL(respack_kernel, dim3(NBH, 4), dim3(256), 0, stream,
                       k, v, samp, kidx, kres, vres);
    hipLaunchKernelGGL(attn_kernel, dim3(NB, NBH), dim3(256), 0, stream,
                       q, k, v, samp, qidx, kidx, kres, vres, out);
}

// Round 12
// 156.661 us; speedup vs baseline: 2.0274x; 2.0274x over previous
//
#include <hip/hip_runtime.h>
#include <hip/hip_bf16.h>
#include <math.h>

#define BD 2
#define HD 16
#define NSEQ 8192
#define DDIM 64
#define NPROJ 7
#define KBLK 256
#define NSAMP 256
#define NBH (BD*HD)           // 32
#define NB (NSEQ/KBLK)        // 32

typedef short bf16x8 __attribute__((ext_vector_type(8)));
typedef short bf16x4 __attribute__((ext_vector_type(4)));
typedef float f32x4 __attribute__((ext_vector_type(4)));

// pack two f32 -> u32 of 2 bf16 (RTNE via v_cvt_pk_bf16_f32)
__device__ __forceinline__ unsigned int pk2bf(float a, float b) {
    union { __hip_bfloat162 h; unsigned int u; } t;
    t.h = __float22bfloat162_rn(make_float2(a, b));
    return t.u;
}

// ---------------------------------------------------------------------------
// Kernel A (fused prelude): q-hash + k-dots + k-norm + per-bh max-norm.
// Dot/norm accumulation kept IDENTICAL across rounds (hash sign bits are
// exact-match-critical).
// ---------------------------------------------------------------------------
__global__ __launch_bounds__(256) void prelude_kernel(const float* __restrict__ q,
                                                      const float* __restrict__ k,
                                                      const float* __restrict__ pd,
                                                      float* __restrict__ kdots,
                                                      unsigned int* __restrict__ kmax_bits,
                                                      unsigned char* __restrict__ qh) {
    __shared__ float pds[(DDIM+1)*NPROJ];
    __shared__ float red[256];
    const int tid = threadIdx.x;
    for (int i = tid; i < (DDIM+1)*NPROJ; i += 256) pds[i] = pd[i];
    __syncthreads();

    const int lin = blockIdx.x * 256 + tid;
    const int bh = lin >> 13;

    float acc[NPROJ];
    float4 xv[16];

    {
        const float4* xp = (const float4*)(q + (size_t)lin * DDIM);
        #pragma unroll
        for (int j = 0; j < 16; ++j) xv[j] = xp[j];
        #pragma unroll
        for (int r = 0; r < NPROJ; ++r) acc[r] = 0.f;
        #pragma unroll
        for (int j = 0; j < 16; ++j) {
            float xs[4] = {xv[j].x, xv[j].y, xv[j].z, xv[j].w};
            #pragma unroll
            for (int c = 0; c < 4; ++c) {
                const int d = j*4 + c;
                #pragma unroll
                for (int r = 0; r < NPROJ; ++r) acc[r] += xs[c] * pds[d*NPROJ + r];
            }
        }
        int bin = 0;
        #pragma unroll
        for (int r = 0; r < NPROJ; ++r) bin |= (acc[r] > 0.f) << r;
        qh[lin] = (unsigned char)(bin ^ (bin >> 1));
    }

    float nr;
    {
        const float4* xp = (const float4*)(k + (size_t)lin * DDIM);
        #pragma unroll
        for (int j = 0; j < 16; ++j) xv[j] = xp[j];
        #pragma unroll
        for (int r = 0; r < NPROJ; ++r) acc[r] = 0.f;
        #pragma unroll
        for (int j = 0; j < 16; ++j) {
            float xs[4] = {xv[j].x, xv[j].y, xv[j].z, xv[j].w};
            #pragma unroll
            for (int c = 0; c < 4; ++c) {
                const int d = j*4 + c;
                #pragma unroll
                for (int r = 0; r < NPROJ; ++r) acc[r] += xs[c] * pds[d*NPROJ + r];
            }
        }
        float ss = 0.f;
        #pragma unroll
        for (int j = 0; j < 16; ++j) {
            float4 t = xv[j];
            ss += t.x*t.x + t.y*t.y + t.z*t.z + t.w*t.w;
        }
        nr = sqrtf(ss);
        float4* kd = (float4*)(kdots + (size_t)lin * 8);
        kd[0] = make_float4(acc[0], acc[1], acc[2], acc[3]);
        kd[1] = make_float4(acc[4], acc[5], acc[6], nr);
    }

    red[tid] = nr;
    __syncthreads();
    for (int s = 128; s > 0; s >>= 1) {
        if (tid < s) red[tid] = fmaxf(red[tid], red[tid+s]);
        __syncthreads();
    }
    if (tid == 0) atomicMax(&kmax_bits[bh], __float_as_uint(red[0]));
}

// ---------------------------------------------------------------------------
// Kernel B: k-hash from stored dots + kmax
// ---------------------------------------------------------------------------
__global__ __launch_bounds__(256) void khash_kernel(const float* __restrict__ pd,
                                                    const float* __restrict__ kdots,
                                                    const unsigned int* __restrict__ kmax_bits,
                                                    unsigned char* __restrict__ kh) {
    const int lin = blockIdx.x * 256 + threadIdx.x;
    const int bh = lin >> 13;
    const float4* kd = (const float4*)(kdots + (size_t)lin * 8);
    float4 d0 = kd[0], d1 = kd[1];
    float acc[NPROJ] = {d0.x, d0.y, d0.z, d0.w, d1.x, d1.y, d1.z};
    const float kn = d1.w;
    const float km = __uint_as_float(kmax_bits[bh]);
    const float ex = sqrtf(fmaxf(km*km - kn*kn, 0.f));
    int bin = 0;
    #pragma unroll
    for (int r = 0; r < NPROJ; ++r) {
        acc[r] += ex * pd[DDIM*NPROJ + r];
        bin |= (acc[r] > 0.f) << r;
    }
    kh[lin] = (unsigned char)(bin ^ (bin >> 1));
}

// ---------------------------------------------------------------------------
// Kernel C: parallel stable counting sort (128 buckets), 256 segs x 32 elems.
// ---------------------------------------------------------------------------
__global__ __launch_bounds__(256) void sort_kernel(const unsigned char* __restrict__ qhash,
                                                   const unsigned char* __restrict__ khash,
                                                   int* __restrict__ qidx,
                                                   int* __restrict__ kidx) {
    __shared__ unsigned char hsh[NSEQ];
    __shared__ unsigned short cnt[128][264];
    __shared__ int base[128];
    __shared__ int wtot[2];
    const int bh = blockIdx.x, tid = threadIdx.x;
    const unsigned char* hash = blockIdx.y ? khash : qhash;
    int* idx = blockIdx.y ? kidx : qidx;

    {
        const uint4* src = (const uint4*)(hash + (size_t)bh * NSEQ);
        uint4* hdst = (uint4*)hsh;
        hdst[tid] = src[tid];
        hdst[tid + 256] = src[tid + 256];
        unsigned int* cz = (unsigned int*)&cnt[0][0];
        for (int i = tid; i < 128*264/2; i += 256) cz[i] = 0;
    }
    __syncthreads();
    {
        const unsigned char* s = hsh + tid*32;
        for (int i = 0; i < 32; ++i) cnt[s[i]][tid]++;
    }
    __syncthreads();

    int sc = 0, vv = 0;
    if (tid < 128) {
        unsigned run = 0;
        uint4* rp = (uint4*)cnt[tid];
        for (int wd = 0; wd < 32; ++wd) {
            uint4 x = rp[wd];
            unsigned v0 = x.x & 0xffffu, v1 = x.x >> 16;
            unsigned v2 = x.y & 0xffffu, v3 = x.y >> 16;
            unsigned v4 = x.z & 0xffffu, v5 = x.z >> 16;
            unsigned v6 = x.w & 0xffffu, v7 = x.w >> 16;
            unsigned p0 = run, p1 = p0+v0, p2 = p1+v1, p3 = p2+v2,
                     p4 = p3+v3, p5 = p4+v4, p6 = p5+v5, p7 = p6+v6;
            run = p7 + v7;
            x.x = p0 | (p1<<16); x.y = p2 | (p3<<16);
            x.z = p4 | (p5<<16); x.w = p6 | (p7<<16);
            rp[wd] = x;
        }
        vv = (int)run;
        sc = vv;
        #pragma unroll
        for (int d = 1; d < 64; d <<= 1) {
            int t = __shfl_up(sc, d, 64);
            if ((tid & 63) >= d) sc += t;
        }
        if ((tid & 63) == 63) wtot[tid >> 6] = sc;
    }
    __syncthreads();
    if (tid < 128) base[tid] = (sc - vv) + (tid >= 64 ? wtot[0] : 0);
    __syncthreads();
    {
        int* dst = idx + (size_t)bh * NSEQ;
        const unsigned char* s = hsh + tid*32;
        for (int i = 0; i < 32; ++i) {
            int h = s[i];
            int c = cnt[h][tid];
            cnt[h][tid] = (unsigned short)(c + 1);
            dst[base[h] + c] = tid*32 + i;
        }
    }
}

#define VSWZ(d) ((((d) >> 1) & 7) << 4)

// ---------------------------------------------------------------------------
// Kernel C2 (respack): residual chunk LDS byte-images (unchanged expressions
// -> images byte-identical to in-kernel staging).
// ---------------------------------------------------------------------------
__global__ __launch_bounds__(256) void respack_kernel(const float* __restrict__ k,
                                                      const float* __restrict__ v,
                                                      const int* __restrict__ samp,
                                                      const int* __restrict__ kidx,
                                                      char* __restrict__ kres,
                                                      char* __restrict__ vres) {
    __shared__ int rows[64];
    const int bh = blockIdx.x, ch = blockIdx.y, tid = threadIdx.x;
    if (tid < 64) rows[tid] = kidx[bh*NSEQ + samp[bh*NSAMP + ch*64 + tid]];
    __syncthreads();
    const size_t basef = (size_t)bh * NSEQ * DDIM;
    char* kimg = kres + (size_t)(bh*4 + ch) * 8192;
    char* vimg = vres + (size_t)(bh*4 + ch) * 8192;

    {
        const int kk = tid & 63, dc = tid >> 6;
        const float* kr = k + basef + (size_t)rows[kk]*DDIM + dc*16;
        float4 f0 = ((const float4*)kr)[0], f1 = ((const float4*)kr)[1];
        float4 f2 = ((const float4*)kr)[2], f3 = ((const float4*)kr)[3];
        union { bf16x8 v8; unsigned int u[4]; } h0, h1;
        h0.u[0] = pk2bf(f0.x,f0.y); h0.u[1] = pk2bf(f0.z,f0.w);
        h0.u[2] = pk2bf(f1.x,f1.y); h0.u[3] = pk2bf(f1.z,f1.w);
        h1.u[0] = pk2bf(f2.x,f2.y); h1.u[1] = pk2bf(f2.z,f2.w);
        h1.u[2] = pk2bf(f3.x,f3.y); h1.u[3] = pk2bf(f3.z,f3.w);
        const int rb = kk*128 + dc*32, sw = (kk & 7) << 4;
        *(bf16x8*)(kimg + ((rb) ^ sw)) = h0.v8;
        *(bf16x8*)(kimg + ((rb + 16) ^ sw)) = h1.v8;
    }
    {
        const int vg = tid & 15, kq = tid >> 4;
        const int r0 = rows[kq*4 + 0], r1 = rows[kq*4 + 1];
        const int r2 = rows[kq*4 + 2], r3 = rows[kq*4 + 3];
        float4 x0 = *(const float4*)(v + basef + (size_t)r0*DDIM + vg*4);
        float4 x1 = *(const float4*)(v + basef + (size_t)r1*DDIM + vg*4);
        float4 x2 = *(const float4*)(v + basef + (size_t)r2*DDIM + vg*4);
        float4 x3 = *(const float4*)(v + basef + (size_t)r3*DDIM + vg*4);
        const float c0[4] = {x0.x, x0.y, x0.z, x0.w};
        const float c1[4] = {x1.x, x1.y, x1.z, x1.w};
        const float c2[4] = {x2.x, x2.y, x2.z, x2.w};
        const float c3[4] = {x3.x, x3.y, x3.z, x3.w};
        #pragma unroll
        for (int j = 0; j < 4; ++j) {
            const int d = vg*4 + j;
            unsigned h01 = pk2bf(c0[j], c1[j]);
            unsigned h23 = pk2bf(c2[j], c3[j]);
            *(uint2*)(vimg + ((d*128 + kq*8) ^ VSWZ(d))) = make_uint2(h01, h23);
        }
    }
}

// ---------------------------------------------------------------------------
// Kernel D: MFMA fused attention, register-resident P, single-buffer staging
// (round-8 structure, byte-identical math). ONE change vs round 8:
// amdgpu_waves_per_eu(2,2) tells the allocator to stop targeting >2 waves/EU
// and use the full 256-VGPR budget, so the 8 gather float4s stay in flight
// (round-8 chose 128 VGPR + spilled + serialized the gathers).
//   QK^T 16x16x32 (Q hi/lo); its C layout (q=lane&15, key=(lane>>4)*4+reg)
//   IS the B-operand layout of 16x16x16bf16_1k => PV from registers.
// ---------------------------------------------------------------------------

#define LN32 3.46573590279972f

template<int PHASE>   // 0 = block-diagonal, 1 = residual
__device__ __forceinline__ void compute_chunk(
    int ch, int lane,
    const bf16x8 (&qhf)[4][2], const bf16x8 (&qlf)[4][2],
    f32x4 (&O)[4][4], float (&lacc)[4],
    const float* maskF, const char* KhL, const char* VthL) {

    const int lr4 = lane >> 4;
    const int lc  = lane & 15;

    #pragma unroll
    for (int mt = 0; mt < 4; ++mt) {
        const int key = mt*16 + lc;
        const int ksw = (key & 7) << 4;
        bf16x8 ka0 = *(const bf16x8*)(KhL + ((key*128 +  0 + lr4*16) ^ ksw));
        bf16x8 ka1 = *(const bf16x8*)(KhL + ((key*128 + 64 + lr4*16) ^ ksw));
        float4 mk;
        if (PHASE) mk = *(const float4*)(maskF + ch*64 + mt*16 + lr4*4);

        bf16x4 pb[4];
        #pragma unroll
        for (int qt = 0; qt < 4; ++qt) {
            f32x4 c = {0.f, 0.f, 0.f, 0.f};
            c = __builtin_amdgcn_mfma_f32_16x16x32_bf16(ka0, qhf[qt][0], c, 0, 0, 0);
            c = __builtin_amdgcn_mfma_f32_16x16x32_bf16(ka0, qlf[qt][0], c, 0, 0, 0);
            c = __builtin_amdgcn_mfma_f32_16x16x32_bf16(ka1, qhf[qt][1], c, 0, 0, 0);
            c = __builtin_amdgcn_mfma_f32_16x16x32_bf16(ka1, qlf[qt][1], c, 0, 0, 0);
            float e0, e1, e2, e3;
            if (PHASE) {
                e0 = __expf(c[0] + LN32) * mk.x;
                e1 = __expf(c[1] + LN32) * mk.y;
                e2 = __expf(c[2] + LN32) * mk.z;
                e3 = __expf(c[3] + LN32) * mk.w;
            } else {
                e0 = __expf(c[0]); e1 = __expf(c[1]);
                e2 = __expf(c[2]); e3 = __expf(c[3]);
            }
            lacc[qt] += (e0+e1) + (e2+e3);
            union { bf16x4 v4; unsigned int u[2]; } pw;
            pw.u[0] = pk2bf(e0, e1);
            pw.u[1] = pk2bf(e2, e3);
            pb[qt] = pw.v4;
        }

        __builtin_amdgcn_s_setprio(1);
        #pragma unroll
        for (int dt = 0; dt < 4; ++dt) {
            const int d = dt*16 + lc;
            bf16x4 va = *(const bf16x4*)(VthL + ((d*128 + mt*32 + lr4*8) ^ VSWZ(d)));
            #pragma unroll
            for (int qt = 0; qt < 4; ++qt)
                O[qt][dt] = __builtin_amdgcn_mfma_f32_16x16x16bf16_1k(va, pb[qt], O[qt][dt], 0, 0, 0);
        }
        __builtin_amdgcn_s_setprio(0);
    }
}

__global__ __launch_bounds__(256)
__attribute__((amdgpu_waves_per_eu(2, 2)))
void attn_kernel(const float* __restrict__ q,
                 const float* __restrict__ k,
                 const float* __restrict__ v,
                 const int* __restrict__ samp,
                 const int* __restrict__ qidx,
                 const int* __restrict__ kidx,
                 const char* __restrict__ kres,
                 const char* __restrict__ vres,
                 float* __restrict__ out) {
    __shared__ __align__(16) char KB[8192];
    __shared__ __align__(16) char VB[8192];
    __shared__ int qidxL[256];
    __shared__ int kidxL[256];
    __shared__ __align__(16) float maskF[256];

    const int g = blockIdx.x, bh = blockIdx.y;
    const int tid = threadIdx.x;
    const int lane = tid & 63, w = tid >> 6;
    const int lr4 = lane >> 4, lc = lane & 15;
    const size_t basef = (size_t)bh * NSEQ * DDIM;

    qidxL[tid] = qidx[bh*NSEQ + g*KBLK + tid];
    kidxL[tid] = kidx[bh*NSEQ + g*KBLK + tid];
    {
        int sp = samp[bh*NSAMP + tid];
        maskF[tid] = ((sp >> 8) == g) ? 0.f : 1.f;
    }
    __syncthreads();

    // Q fragments (hi/lo), pre-scaled by 0.125 (exact)
    bf16x8 qhf[4][2], qlf[4][2];
    #pragma unroll
    for (int qt = 0; qt < 4; ++qt) {
        const int qrow = qidxL[w*64 + qt*16 + lc];
        const float* qp = q + basef + (size_t)qrow*DDIM;
        #pragma unroll
        for (int ks = 0; ks < 2; ++ks) {
            const float* p = qp + ks*32 + lr4*8;
            float4 a = *(const float4*)p;
            float4 b = *(const float4*)(p + 4);
            float xs[8] = {a.x,a.y,a.z,a.w,b.x,b.y,b.z,b.w};
            union { bf16x8 v8; unsigned int u[4]; } hv, lv;
            #pragma unroll
            for (int j = 0; j < 4; ++j) {
                float s0 = xs[2*j]   * 0.125f;
                float s1 = xs[2*j+1] * 0.125f;
                unsigned hp = pk2bf(s0, s1);
                hv.u[j] = hp;
                float l0 = s0 - __uint_as_float(hp << 16);
                float l1 = s1 - __uint_as_float(hp & 0xffff0000u);
                lv.u[j] = pk2bf(l0, l1);
            }
            qhf[qt][ks] = hv.v8; qlf[qt][ks] = lv.v8;
        }
    }

    f32x4 O[4][4];
    #pragma unroll
    for (int a = 0; a < 4; ++a)
        #pragma unroll
        for (int b = 0; b < 4; ++b) O[a][b] = (f32x4){0.f,0.f,0.f,0.f};
    float lacc[4] = {0,0,0,0};

    const int kk = tid & 63, dcw = tid >> 6;     // K-stage mapping
    const int vg = tid & 15, kq = tid >> 4;      // V-stage mapping

    // ==== PHASE 0: block-diagonal (gather-staged), 4 chunks ====
    for (int ch = 0; ch < 4; ++ch) {
        __syncthreads();
        {
            const int korig = kidxL[ch*64 + kk];
            const float* kr = k + basef + (size_t)korig*DDIM + dcw*16;
            float4 f0 = ((const float4*)kr)[0], f1 = ((const float4*)kr)[1];
            float4 f2 = ((const float4*)kr)[2], f3 = ((const float4*)kr)[3];
            union { bf16x8 v8; unsigned int u[4]; } h0, h1;
            h0.u[0] = pk2bf(f0.x,f0.y); h0.u[1] = pk2bf(f0.z,f0.w);
            h0.u[2] = pk2bf(f1.x,f1.y); h0.u[3] = pk2bf(f1.z,f1.w);
            h1.u[0] = pk2bf(f2.x,f2.y); h1.u[1] = pk2bf(f2.z,f2.w);
            h1.u[2] = pk2bf(f3.x,f3.y); h1.u[3] = pk2bf(f3.z,f3.w);
            const int rb = kk*128 + dcw*32, sw2 = (kk & 7) << 4;
            *(bf16x8*)(KB + ((rb) ^ sw2)) = h0.v8;
            *(bf16x8*)(KB + ((rb + 16) ^ sw2)) = h1.v8;
        }
        {
            const int r0 = kidxL[ch*64 + kq*4 + 0];
            const int r1 = kidxL[ch*64 + kq*4 + 1];
            const int r2 = kidxL[ch*64 + kq*4 + 2];
            const int r3 = kidxL[ch*64 + kq*4 + 3];
            float4 x0 = *(const float4*)(v + basef + (size_t)r0*DDIM + vg*4);
            float4 x1 = *(const float4*)(v + basef + (size_t)r1*DDIM + vg*4);
            float4 x2 = *(const float4*)(v + basef + (size_t)r2*DDIM + vg*4);
            float4 x3 = *(const float4*)(v + basef + (size_t)r3*DDIM + vg*4);
            const float c0[4] = {x0.x, x0.y, x0.z, x0.w};
            const float c1[4] = {x1.x, x1.y, x1.z, x1.w};
            const float c2[4] = {x2.x, x2.y, x2.z, x2.w};
            const float c3[4] = {x3.x, x3.y, x3.z, x3.w};
            #pragma unroll
            for (int j = 0; j < 4; ++j) {
                const int d = vg*4 + j;
                unsigned h01 = pk2bf(c0[j], c1[j]);
                unsigned h23 = pk2bf(c2[j], c3[j]);
                *(uint2*)(VB + ((d*128 + kq*8) ^ VSWZ(d))) = make_uint2(h01, h23);
            }
        }
        __syncthreads();
        compute_chunk<0>(ch, lane, qhf, qlf, O, lacc, maskF, KB, VB);
    }

    // ==== PHASE 1: residual (prepacked image copy), 4 chunks ====
    for (int ch = 0; ch < 4; ++ch) {
        __syncthreads();
        {
            const char* ksrc = kres + (size_t)(bh*4 + ch) * 8192 + tid*32;
            const char* vsrc = vres + (size_t)(bh*4 + ch) * 8192 + tid*32;
            float4 a0 = ((const float4*)ksrc)[0];
            float4 a1 = ((const float4*)ksrc)[1];
            float4 b0 = ((const float4*)vsrc)[0];
            float4 b1 = ((const float4*)vsrc)[1];
            *(float4*)(KB + tid*32)      = a0;
            *(float4*)(KB + tid*32 + 16) = a1;
            *(float4*)(VB + tid*32)      = b0;
            *(float4*)(VB + tid*32 + 16) = b1;
        }
        __syncthreads();
        compute_chunk<1>(ch, lane, qhf, qlf, O, lacc, maskF, KB, VB);
    }

    // ---- epilogue: O^T layout => q = lane&15 (matches lacc), d contiguous ----
    #pragma unroll
    for (int qt = 0; qt < 4; ++qt) {
        lacc[qt] += __shfl_xor(lacc[qt], 16, 64);
        lacc[qt] += __shfl_xor(lacc[qt], 32, 64);
        lacc[qt] = 1.f / lacc[qt];
    }
    float* ob = out + basef;
    #pragma unroll
    for (int qt = 0; qt < 4; ++qt) {
        const int orow = qidxL[w*64 + qt*16 + lc];
        const float f = lacc[qt];
        float* p = ob + (size_t)orow*DDIM + lr4*4;
        #pragma unroll
        for (int dt = 0; dt < 4; ++dt) {
            float4 st = make_float4(O[qt][dt][0]*f, O[qt][dt][1]*f,
                                    O[qt][dt][2]*f, O[qt][dt][3]*f);
            *(float4*)(p + dt*16) = st;
        }
    }
}

// ---------------------------------------------------------------------------
extern "C" void kernel_launch(void* const* d_in, const int* in_sizes, int n_in,
                              void* d_out, int out_size, void* d_ws, size_t ws_size,
                              hipStream_t stream) {
    const float* q    = (const float*)d_in[0];
    const float* k    = (const float*)d_in[1];
    const float* v    = (const float*)d_in[2];
    const float* pd   = (const float*)d_in[3];
    const int*   samp = (const int*)d_in[4];
    float* out = (float*)d_out;

    char* ws = (char*)d_ws;
    // kdots occupies [0, 8 MB) and is dead after khash; qidx/kidx/kres/vres
    // overlay that region afterwards.
    float*         kdots = (float*)(ws + 0);
    int*           qidx  = (int*)(ws + 0);
    int*           kidx  = (int*)(ws + 1048576);
    char*          kres  = ws + 2097152;
    char*          vres  = ws + 3145728;
    unsigned char* qh    = (unsigned char*)(ws + 8388608);
    unsigned char* kh    = (unsigned char*)(ws + 8650752);
    unsigned int*  kmaxb = (unsigned int*)(ws + 8912896);

    hipMemsetAsync(kmaxb, 0, NBH*sizeof(unsigned int), stream);
    hipLaunchKernelGGL(prelude_kernel, dim3(NBH*NSEQ/256), dim3(256), 0, stream,
                       q, k, pd, kdots, kmaxb, qh);
    hipLaunchKernelGGL(khash_kernel, dim3(NBH*NSEQ/256), dim3(256), 0, stream,
                       pd, kdots, kmaxb, kh);
    hipLaunchKernelGGL(sort_kernel, dim3(NBH, 2), dim3(256), 0, stream, qh, kh, qidx, kidx);
    hipLaunchKernelGGL(respack_kernel, dim3(NBH, 4), dim3(256), 0, stream,
                       k, v, samp, kidx, kres, vres);
    hipLaunchKernelGGL(attn_kernel, dim3(NB, NBH), dim3(256), 0, stream,
                       q, k, v, samp, qidx, kidx, kres, vres, out);
}